// Round 4
// baseline (219.228 us; speedup 1.0000x reference)
//
#include <hip/hip_runtime.h>

#define TT 512
#define DD 256
#define BB 2
#define MM (BB*TT)          // 1024
#define LCH 16              // wkv chunk length
#define NBLK 256            // persistent grid

// Device-scope grid barrier (cnt/flag zeroed by memset node before launch).
__device__ __forceinline__ void grid_barrier(int* cnt, int* flag)
{
    __syncthreads();
    if (threadIdx.x == 0) {
        __threadfence();   // agent-scope release of this block's stores
        int v = __hip_atomic_fetch_add(cnt, 1, __ATOMIC_ACQ_REL,
                                       __HIP_MEMORY_SCOPE_AGENT);
        if (v == NBLK - 1) {
            __hip_atomic_store(flag, 1, __ATOMIC_RELEASE,
                               __HIP_MEMORY_SCOPE_AGENT);
        } else {
            while (!__hip_atomic_load(flag, __ATOMIC_ACQUIRE,
                                      __HIP_MEMORY_SCOPE_AGENT))
                __builtin_amdgcn_s_sleep(4);
        }
        __threadfence();   // agent-scope acquire before reading others' data
    }
    __syncthreads();
}

// ---------------------------------------------------------------------------
// Fused persistent kernel: 256 blocks x 256 threads.
// Phase 1: k/v/r mixed GEMMs (one 32t x 32n tile per block, all 3 mats,
//          shared X loads), outputs transposed (B,D,T).
// Phase 2: blocks 0..63 run the chunked-scan WKV (+ tail outputs).
// Phase 3: out = y^T @ Wo^T, one 32t x 32n tile per block.
// LDS: Bs tiles XOR-swizzled (kq ^= row&15, stride 64) -> staging writes and
// inner b128 reads both at the LDS data-volume floor.  As reads broadcast.
// ---------------------------------------------------------------------------
__global__ __launch_bounds__(256)
void rwkv_fused(const float* __restrict__ x,    const float* __restrict__ xlast,
                const float* __restrict__ lnum, const float* __restrict__ lden,
                const float* __restrict__ td,   const float* __restrict__ tf,
                const float* __restrict__ mk,   const float* __restrict__ mvx,
                const float* __restrict__ mr,
                const float* __restrict__ Wk,   const float* __restrict__ Wv,
                const float* __restrict__ Wr,   const float* __restrict__ Wo,
                float* __restrict__ kT, float* __restrict__ vT,
                float* __restrict__ rT, float* __restrict__ yT,
                float* __restrict__ out, int* __restrict__ bar)
{
    __shared__ union {
        struct { float A[3][32][64]; float B[3][32][64]; } p1;   // 48 KB
        struct { float A[64][32];    float B[32][64];    } p3;   // 16 KB
    } sm;

    const int bid = blockIdx.x;
    const int tid = threadIdx.x;

    // ---------------- Phase 1: mixed GEMMs ----------------
    {
        const float* Wm[3] = { Wk, Wv, Wr };
        const float* mx[3] = { mk, mvx, mr };
        float*       Om[3] = { kT, vT, rT };

        const int n0 = (bid & 7) * 32;
        const int m0 = (bid >> 3) * 32;
        const int b  = m0 >> 9;
        const int t0 = m0 & (TT - 1);

        const int row0 = tid >> 4;      // 0..15
        const int cq   = tid & 15;      // k float4-quad within 64-chunk
        const int tm   = tid >> 5;      // 0..7
        const int tn   = tid & 31;      // 0..31

        float4 acc[3] = { {0,0,0,0}, {0,0,0,0}, {0,0,0,0} };

        for (int c = 0; c < 4; ++c) {
            const int k0 = c * 64;
            #pragma unroll
            for (int p = 0; p < 2; ++p) {
                const int row = row0 + p * 16;
                const float4 xc = *(const float4*)&x[(m0 + row) * DD + k0 + cq * 4];
                float4 xp;
                if (t0 + row == 0) xp = *(const float4*)&xlast[b * DD + k0 + cq * 4];
                else               xp = *(const float4*)&x[(m0 + row - 1) * DD + k0 + cq * 4];
                #pragma unroll
                for (int m = 0; m < 3; ++m) {
                    const float4 mv = *(const float4*)&mx[m][k0 + cq * 4];
                    float4 a;
                    a.x = xp.x + (xc.x - xp.x) * mv.x;
                    a.y = xp.y + (xc.y - xp.y) * mv.y;
                    a.z = xp.z + (xc.z - xp.z) * mv.z;
                    a.w = xp.w + (xc.w - xp.w) * mv.w;
                    *(float4*)&sm.p1.A[m][row][cq * 4] = a;
                    const float4 wv = *(const float4*)&Wm[m][(n0 + row) * DD + k0 + cq * 4];
                    *(float4*)&sm.p1.B[m][row][(cq ^ (row & 15)) * 4] = wv;
                }
            }
            __syncthreads();
            #pragma unroll
            for (int k4 = 0; k4 < 16; ++k4) {
                #pragma unroll
                for (int m = 0; m < 3; ++m) {
                    const float4 bq = *(const float4*)&sm.p1.B[m][tn][(k4 ^ (tn & 15)) * 4];
                    float* ac = (float*)&acc[m];
                    #pragma unroll
                    for (int i = 0; i < 4; ++i) {
                        const float4 aq = *(const float4*)&sm.p1.A[m][tm * 4 + i][k4 * 4];
                        ac[i] = fmaf(aq.x, bq.x, ac[i]);
                        ac[i] = fmaf(aq.y, bq.y, ac[i]);
                        ac[i] = fmaf(aq.z, bq.z, ac[i]);
                        ac[i] = fmaf(aq.w, bq.w, ac[i]);
                    }
                }
            }
            __syncthreads();
        }
        #pragma unroll
        for (int m = 0; m < 3; ++m)
            *(float4*)&Om[m][(size_t)(b * DD + n0 + tn) * TT + t0 + tm * 4] = acc[m];
    }

    grid_barrier(bar, bar + 1);

    // ---------------- Phase 2: WKV chunked scan (blocks 0..63) ----------------
    if (bid < 64) {
        const int ch   = bid * 8 + (tid >> 5);
        const int lane = tid & 31;
        const int b    = ch >> 8;
        const int d    = ch & (DD - 1);

        const float w  = -__expf(td[d]);
        const float ew = __expf(w);
        const float eu = __expf(tf[d]);

        const size_t base = (size_t)ch * TT + lane * LCH;
        float k_[LCH], v_[LCH], r_[LCH];
        #pragma unroll
        for (int i = 0; i < 4; ++i) {
            *(float4*)&k_[4 * i] = *(const float4*)(kT + base + 4 * i);
            *(float4*)&v_[4 * i] = *(const float4*)(vT + base + 4 * i);
            *(float4*)&r_[4 * i] = *(const float4*)(rT + base + 4 * i);
        }

        float ek[LCH], ekv[LCH], sr[LCH];
        #pragma unroll
        for (int i = 0; i < LCH; ++i) {
            ek[i]  = __expf(k_[i]);
            ekv[i] = ek[i] * v_[i];
            sr[i]  = __builtin_amdgcn_rcpf(1.0f + __expf(-r_[i]));
        }

        float A = __expf(w * (float)LCH);
        float Bn = 0.0f, Bd = 0.0f;
        #pragma unroll
        for (int i = 0; i < LCH; ++i) {
            Bn = fmaf(ew, Bn, ekv[i]);
            Bd = fmaf(ew, Bd, ek[i]);
        }

        #pragma unroll
        for (int s = 1; s < 32; s <<= 1) {
            const float Ax  = __shfl_up(A, s, 32);
            const float Bnx = __shfl_up(Bn, s, 32);
            const float Bdx = __shfl_up(Bd, s, 32);
            if (lane >= s) {
                Bn = fmaf(A, Bnx, Bn);
                Bd = fmaf(A, Bdx, Bd);
                A *= Ax;
            }
        }

        float Aex  = __shfl_up(A, 1, 32);
        float Bnex = __shfl_up(Bn, 1, 32);
        float Bdex = __shfl_up(Bd, 1, 32);
        if (lane == 0) { Aex = 1.0f; Bnex = 0.0f; Bdex = 0.0f; }
        float sn = fmaf(Aex, lnum[ch], Bnex);
        float sd = fmaf(Aex, lden[ch], Bdex);

        float y_[LCH];
        #pragma unroll
        for (int i = 0; i < LCH; ++i) {
            const float euk = eu * ek[i];
            const float wkv = (sn + eu * ekv[i]) * __builtin_amdgcn_rcpf(sd + euk);
            y_[i] = wkv * sr[i];
            sn = fmaf(ew, sn, ekv[i]);
            sd = fmaf(ew, sd, ek[i]);
        }
        #pragma unroll
        for (int i = 0; i < 4; ++i)
            *(float4*)(yT + base + 4 * i) = *(const float4*)&y_[4 * i];

        if (lane == 31) {
            out[MM * DD + BB * DD + ch]     = sn;
            out[MM * DD + 2 * BB * DD + ch] = sd;
        }
        if (lane == 0)
            out[MM * DD + ch] = x[(b * TT + TT - 1) * DD + d];
    }

    grid_barrier(bar + 2, bar + 3);

    // ---------------- Phase 3: out = y^T @ Wo^T ----------------
    {
        const int n0 = (bid & 7) * 32;
        const int m0 = (bid >> 3) * 32;
        const int b  = m0 >> 9;
        const int t0 = m0 & (TT - 1);

        const int tm = tid >> 5;        // 0..7
        const int tn = tid & 31;        // 0..31

        const int rowA = tid >> 3;      // 0..31 (k), +32 for p=1
        const int cqA  = tid & 7;       // t quad
        const int rowB = tid >> 4;      // 0..15 (n), +16
        const int cqB  = tid & 15;      // k quad

        float acc[4] = {0.f, 0.f, 0.f, 0.f};

        for (int c = 0; c < 4; ++c) {
            const int k0 = c * 64;
            #pragma unroll
            for (int p = 0; p < 2; ++p) {
                const int ra = rowA + p * 32;
                *(float4*)&sm.p3.A[ra][cqA * 4] =
                    *(const float4*)&yT[(size_t)(b * DD + k0 + ra) * TT + t0 + cqA * 4];
                const int rb = rowB + p * 16;
                *(float4*)&sm.p3.B[rb][(cqB ^ (rb & 15)) * 4] =
                    *(const float4*)&Wo[(n0 + rb) * DD + k0 + cqB * 4];
            }
            __syncthreads();
            #pragma unroll
            for (int k4 = 0; k4 < 16; ++k4) {
                const float4 bq = *(const float4*)&sm.p3.B[tn][(k4 ^ (tn & 15)) * 4];
                const float bb[4] = {bq.x, bq.y, bq.z, bq.w};
                #pragma unroll
                for (int j = 0; j < 4; ++j) {
                    const float4 aq = *(const float4*)&sm.p3.A[k4 * 4 + j][tm * 4];
                    acc[0] = fmaf(aq.x, bb[j], acc[0]);
                    acc[1] = fmaf(aq.y, bb[j], acc[1]);
                    acc[2] = fmaf(aq.z, bb[j], acc[2]);
                    acc[3] = fmaf(aq.w, bb[j], acc[3]);
                }
            }
            __syncthreads();
        }

        #pragma unroll
        for (int i = 0; i < 4; ++i)
            out[(size_t)(m0 + tm * 4 + i) * DD + n0 + tn] = acc[i];
    }
}

// ---------------------------------------------------------------------------
extern "C" void kernel_launch(void* const* d_in, const int* in_sizes, int n_in,
                              void* d_out, int out_size, void* d_ws, size_t ws_size,
                              hipStream_t stream)
{
    const float* x    = (const float*)d_in[0];
    const float* lx   = (const float*)d_in[1];
    const float* lnum = (const float*)d_in[2];
    const float* lden = (const float*)d_in[3];
    const float* td   = (const float*)d_in[4];
    const float* tf   = (const float*)d_in[5];
    const float* mk   = (const float*)d_in[6];
    const float* mv   = (const float*)d_in[7];
    const float* mr   = (const float*)d_in[8];
    const float* Wk   = (const float*)d_in[9];
    const float* Wv   = (const float*)d_in[10];
    const float* Wr   = (const float*)d_in[11];
    const float* Wo   = (const float*)d_in[12];
    float* out = (float*)d_out;

    float* kT = (float*)d_ws;          // (B, D, T)
    float* vT = kT + MM * DD;
    float* rT = vT + MM * DD;
    float* yT = rT + MM * DD;
    int*   bar = (int*)(yT + MM * DD); // 4 ints: 2 x (cnt, flag)

    hipMemsetAsync(bar, 0, 4 * sizeof(int), stream);

    rwkv_fused<<<dim3(NBLK), 256, 0, stream>>>(
        x, lx, lnum, lden, td, tf, mk, mv, mr, Wk, Wv, Wr, Wo,
        kT, vT, rT, yT, out, bar);
}

// Round 5
// 110.454 us; speedup vs baseline: 1.9848x; 1.9848x over previous
//
#include <hip/hip_runtime.h>

#define TT 512
#define DD 256
#define BB 2
#define MM (BB*TT)          // 1024
#define LCH 16              // wkv chunk length
#define NCH (TT/LCH)        // 32 chunks per channel

// ---------------------------------------------------------------------------
// K1: k/v/r = timemix(X) @ W^T, stored TRANSPOSED as (B, D, T) for the scan.
// Tile 64(m=T) x 32(n), 128 threads, 4x4 microtile, K-chunks of 64.
// Staging is coalesced (16 lanes x 256B rows) with LDS transpose; pads 68/36
// keep inner ds_read_b128 16B-aligned.  r is stored RAW (sigmoid in K2).
// NOTE (R4 post-mortem): do NOT fuse these stages with grid barriers — on
// MI355X the agent-scope fences cost ~50-70us in serialized L2 wb/inv,
// far more than the ~2-3us a launch boundary costs.
// ---------------------------------------------------------------------------
__global__ __launch_bounds__(128)
void gemm_mix_t(const float* __restrict__ X, const float* __restrict__ Xlast,
                const float* __restrict__ W0, const float* __restrict__ W1,
                const float* __restrict__ W2,
                const float* __restrict__ mx0, const float* __restrict__ mx1,
                const float* __restrict__ mx2,
                float* __restrict__ O0, float* __restrict__ O1,
                float* __restrict__ O2)
{
    const int mat = blockIdx.z;
    const float* W  = (mat == 0) ? W0  : (mat == 1) ? W1  : W2;
    const float* mx = (mat == 0) ? mx0 : (mat == 1) ? mx1 : mx2;
    float*       O  = (mat == 0) ? O0  : (mat == 1) ? O1  : O2;

    const int n0  = blockIdx.x * 32;
    const int m0  = blockIdx.y * 64;
    const int b   = m0 / TT;
    const int t0  = m0 % TT;
    const int tid = threadIdx.x;

    const int cc = (tid & 15) * 4;   // k offset within chunk (staging)
    const int r8 = tid >> 4;         // 0..7
    const int tm = tid >> 3;         // 0..15 (m groups of 4)
    const int tn = tid & 7;          // 0..7  (n groups of 4)

    __shared__ float As[64][68];     // [k][m], pad 68 (16B-aligned rows)
    __shared__ float Bs[64][36];     // [k][n], pad 36

    float acc[4][4] = {};

    for (int k0 = 0; k0 < DD; k0 += 64) {
        // stage A: 64 rows (t), 64 k, coalesced, mix applied
        #pragma unroll
        for (int i = 0; i < 8; ++i) {
            const int rr  = r8 + i * 8;
            const int row = m0 + rr;
            const float4 xc = *(const float4*)&X[row * DD + k0 + cc];
            float4 xp;
            if (t0 + rr == 0) xp = *(const float4*)&Xlast[b * DD + k0 + cc];
            else              xp = *(const float4*)&X[(row - 1) * DD + k0 + cc];
            const float4 mv = *(const float4*)&mx[k0 + cc];
            As[cc + 0][rr] = xp.x + (xc.x - xp.x) * mv.x;
            As[cc + 1][rr] = xp.y + (xc.y - xp.y) * mv.y;
            As[cc + 2][rr] = xp.z + (xc.z - xp.z) * mv.z;
            As[cc + 3][rr] = xp.w + (xc.w - xp.w) * mv.w;
        }
        // stage B: 32 rows of W, 64 k, coalesced
        #pragma unroll
        for (int i = 0; i < 4; ++i) {
            const int rr = r8 + i * 8;
            const float4 wv = *(const float4*)&W[(n0 + rr) * DD + k0 + cc];
            Bs[cc + 0][rr] = wv.x;
            Bs[cc + 1][rr] = wv.y;
            Bs[cc + 2][rr] = wv.z;
            Bs[cc + 3][rr] = wv.w;
        }
        __syncthreads();
        #pragma unroll
        for (int kk = 0; kk < 64; ++kk) {
            const float4 a4 = *(const float4*)&As[kk][tm * 4];
            const float4 b4 = *(const float4*)&Bs[kk][tn * 4];
            const float am[4] = {a4.x, a4.y, a4.z, a4.w};
            const float bn[4] = {b4.x, b4.y, b4.z, b4.w};
            #pragma unroll
            for (int i = 0; i < 4; ++i)
                #pragma unroll
                for (int j = 0; j < 4; ++j)
                    acc[i][j] = fmaf(am[i], bn[j], acc[i][j]);
        }
        __syncthreads();
    }

    // store transposed: O[(b, n, t)] ; t = t0 + tm*4 + i, n = n0 + tn*4 + j
    #pragma unroll
    for (int j = 0; j < 4; ++j) {
        const float4 o = make_float4(acc[0][j], acc[1][j], acc[2][j], acc[3][j]);
        *(float4*)&O[(size_t)(b * DD + n0 + tn * 4 + j) * TT + t0 + tm * 4] = o;
    }
}

// ---------------------------------------------------------------------------
// K2: WKV via chunked parallel scan.  64 blocks x 256 thr.
// Thread = (channel, chunk): ch = bid*8 + (tid>>5), chunk = tid&31 (L=16).
// Local Horner sums -> shfl_up scan over 32 chunks -> replay 16 steps.
// ---------------------------------------------------------------------------
__global__ __launch_bounds__(256)
void wkv_scan(const float* __restrict__ kT, const float* __restrict__ vT,
              const float* __restrict__ rT, const float* __restrict__ x,
              const float* __restrict__ last_num, const float* __restrict__ last_den,
              const float* __restrict__ time_decay, const float* __restrict__ time_first,
              float* __restrict__ yT, float* __restrict__ out)
{
    const int tid  = threadIdx.x;
    const int ch   = blockIdx.x * 8 + (tid >> 5);
    const int lane = tid & 31;           // chunk index
    const int b    = ch >> 8;
    const int d    = ch & (DD - 1);

    const float w  = -__expf(time_decay[d]);
    const float ew = __expf(w);
    const float eu = __expf(time_first[d]);

    const size_t base = (size_t)ch * TT + lane * LCH;
    float k_[LCH], v_[LCH], r_[LCH];
    #pragma unroll
    for (int i = 0; i < 4; ++i) {
        *(float4*)&k_[4 * i] = *(const float4*)(kT + base + 4 * i);
        *(float4*)&v_[4 * i] = *(const float4*)(vT + base + 4 * i);
        *(float4*)&r_[4 * i] = *(const float4*)(rT + base + 4 * i);
    }

    float ek[LCH], ekv[LCH], sr[LCH];
    #pragma unroll
    for (int i = 0; i < LCH; ++i) {
        ek[i]  = __expf(k_[i]);
        ekv[i] = ek[i] * v_[i];
        sr[i]  = __builtin_amdgcn_rcpf(1.0f + __expf(-r_[i]));
    }

    float A = __expf(w * (float)LCH);
    float Bn = 0.0f, Bd = 0.0f;
    #pragma unroll
    for (int i = 0; i < LCH; ++i) {
        Bn = fmaf(ew, Bn, ekv[i]);
        Bd = fmaf(ew, Bd, ek[i]);
    }

    #pragma unroll
    for (int s = 1; s < 32; s <<= 1) {
        const float Ax  = __shfl_up(A, s, 32);
        const float Bnx = __shfl_up(Bn, s, 32);
        const float Bdx = __shfl_up(Bd, s, 32);
        if (lane >= s) {
            Bn = fmaf(A, Bnx, Bn);
            Bd = fmaf(A, Bdx, Bd);
            A *= Ax;
        }
    }

    float Aex  = __shfl_up(A, 1, 32);
    float Bnex = __shfl_up(Bn, 1, 32);
    float Bdex = __shfl_up(Bd, 1, 32);
    if (lane == 0) { Aex = 1.0f; Bnex = 0.0f; Bdex = 0.0f; }
    float sn = fmaf(Aex, last_num[ch], Bnex);
    float sd = fmaf(Aex, last_den[ch], Bdex);

    float y_[LCH];
    #pragma unroll
    for (int i = 0; i < LCH; ++i) {
        const float euk = eu * ek[i];
        const float wkv = (sn + eu * ekv[i]) * __builtin_amdgcn_rcpf(sd + euk);
        y_[i] = wkv * sr[i];
        sn = fmaf(ew, sn, ekv[i]);
        sd = fmaf(ew, sd, ek[i]);
    }
    #pragma unroll
    for (int i = 0; i < 4; ++i)
        *(float4*)(yT + base + 4 * i) = *(const float4*)&y_[4 * i];

    if (lane == 31) {
        out[MM * DD + BB * DD + ch]     = sn;
        out[MM * DD + 2 * BB * DD + ch] = sd;
    }
    if (lane == 0)
        out[MM * DD + ch] = x[(b * TT + TT - 1) * DD + d];
}

// ---------------------------------------------------------------------------
// K3: out = yT^T @ Wo^T.  A comes pre-transposed (B,D,T) -> direct b128 LDS
// stage.  Tile 32(t) x 32(n), 64 threads (1 wave), 4x4 micro, 256 blocks.
// ---------------------------------------------------------------------------
__global__ __launch_bounds__(64)
void gemm_out(const float* __restrict__ yT, const float* __restrict__ Wo,
              float* __restrict__ O)
{
    const int n0  = blockIdx.x * 32;
    const int m0  = blockIdx.y * 32;
    const int b   = m0 >> 9;            // /TT
    const int t0  = m0 & (TT - 1);
    const int tid = threadIdx.x;

    __shared__ float As[64][36];        // [k][t]
    __shared__ float Bs[64][36];        // [k][n]

    const int tm = tid >> 3;            // 0..7
    const int tn = tid & 7;             // 0..7

    float acc[4][4] = {};

    for (int k0 = 0; k0 < DD; k0 += 64) {
        // stage A: direct copy from (D,T) layout, b128 LDS writes
        {
            const int mq = (tid & 7) * 4;
            #pragma unroll
            for (int i = 0; i < 8; ++i) {
                const int kk = (tid >> 3) + i * 8;
                *(float4*)&As[kk][mq] =
                    *(const float4*)&yT[(size_t)(b * DD + k0 + kk) * TT + t0 + mq];
            }
        }
        // stage B: coalesced rows of Wo, transpose into LDS
        {
            const int cc = (tid & 15) * 4;
            #pragma unroll
            for (int i = 0; i < 8; ++i) {
                const int rr = (tid >> 4) + i * 4;   // 0..31
                const float4 wv = *(const float4*)&Wo[(n0 + rr) * DD + k0 + cc];
                Bs[cc + 0][rr] = wv.x;
                Bs[cc + 1][rr] = wv.y;
                Bs[cc + 2][rr] = wv.z;
                Bs[cc + 3][rr] = wv.w;
            }
        }
        __syncthreads();
        #pragma unroll
        for (int kk = 0; kk < 64; ++kk) {
            const float4 a4 = *(const float4*)&As[kk][tm * 4];
            const float4 b4 = *(const float4*)&Bs[kk][tn * 4];
            const float am[4] = {a4.x, a4.y, a4.z, a4.w};
            const float bn[4] = {b4.x, b4.y, b4.z, b4.w};
            #pragma unroll
            for (int i = 0; i < 4; ++i)
                #pragma unroll
                for (int j = 0; j < 4; ++j)
                    acc[i][j] = fmaf(am[i], bn[j], acc[i][j]);
        }
        __syncthreads();
    }

    #pragma unroll
    for (int i = 0; i < 4; ++i) {
        const float4 o = make_float4(acc[i][0], acc[i][1], acc[i][2], acc[i][3]);
        *(float4*)&O[(size_t)(m0 + tm * 4 + i) * DD + n0 + tn * 4] = o;
    }
}

// ---------------------------------------------------------------------------
extern "C" void kernel_launch(void* const* d_in, const int* in_sizes, int n_in,
                              void* d_out, int out_size, void* d_ws, size_t ws_size,
                              hipStream_t stream)
{
    const float* x    = (const float*)d_in[0];
    const float* lx   = (const float*)d_in[1];
    const float* lnum = (const float*)d_in[2];
    const float* lden = (const float*)d_in[3];
    const float* td   = (const float*)d_in[4];
    const float* tf   = (const float*)d_in[5];
    const float* mk   = (const float*)d_in[6];
    const float* mv   = (const float*)d_in[7];
    const float* mr   = (const float*)d_in[8];
    const float* Wk   = (const float*)d_in[9];
    const float* Wv   = (const float*)d_in[10];
    const float* Wr   = (const float*)d_in[11];
    const float* Wo   = (const float*)d_in[12];
    float* out = (float*)d_out;

    float* kT = (float*)d_ws;          // (B, D, T)
    float* vT = kT + MM * DD;
    float* rT = vT + MM * DD;          // raw r (sigmoid applied in K2)
    float* yT = rT + MM * DD;          // (B, D, T) = wkv * sigmoid(r)

    gemm_mix_t<<<dim3(8, 16, 3), 128, 0, stream>>>(
        x, lx, Wk, Wv, Wr, mk, mv, mr, kT, vT, rT);

    wkv_scan<<<dim3(64), 256, 0, stream>>>(
        kT, vT, rT, x, lnum, lden, td, tf, yT, out);

    gemm_out<<<dim3(8, 32), 64, 0, stream>>>(yT, Wo, out);
}